// Round 3
// baseline (309.750 us; speedup 1.0000x reference)
//
#include <hip/hip_runtime.h>
#include <hip/hip_bf16.h>

#define NN 256
#define LL 128
#define BSZ 16
#define RR (BSZ * LL)   // 2048 rows

// ---------------------------------------------------------------------------
// Weight transpose: Wt[k][c] = W[c][k].  12 matrices of 256x256.
// grid (16 tiles, 12 mats), 256 threads. Tile 64x64 via LDS.
// mat 0..2:  aggW[i]            (stride 256, off 0)
// mat 3..5:  attnW[i][:, :256]  (stride 512, off 0)    -> W1t
// mat 6..8:  updW[i][:, :256]   (stride 512, off 0)    -> U1t
// mat 9..11: updW[i][:, 256:]   (stride 512, off 256)  -> U2t
// ---------------------------------------------------------------------------
__global__ __launch_bounds__(256) void trans_k(
    const float* __restrict__ aggW,
    const float* __restrict__ attnW,
    const float* __restrict__ updW,
    float* __restrict__ WtBase)     // 12 * 65536 floats
{
    __shared__ float Tl[64][65];
    const int m = blockIdx.y;
    const int t = blockIdx.x;
    const int tr = t >> 2, tc = t & 3;     // src row-tile, col-tile
    const float* src; int stride, off;
    if (m < 3)       { src = aggW  + (size_t)m * NN * NN;           stride = NN;     off = 0;  }
    else if (m < 6)  { src = attnW + (size_t)(m - 3) * NN * 2 * NN; stride = 2 * NN; off = 0;  }
    else if (m < 9)  { src = updW  + (size_t)(m - 6) * NN * 2 * NN; stride = 2 * NN; off = 0;  }
    else             { src = updW  + (size_t)(m - 9) * NN * 2 * NN; stride = 2 * NN; off = NN; }
    float* dst = WtBase + (size_t)m * NN * NN;

    const int rl = threadIdx.x >> 4;        // 0..15
    const int q  = threadIdx.x & 15;        // 0..15
    #pragma unroll
    for (int rr = 0; rr < 4; rr++) {
        const int row = tr * 64 + rr * 16 + rl;
        const float4 v = *(const float4*)(src + (size_t)row * stride + off + tc * 64 + q * 4);
        Tl[rr * 16 + rl][q * 4 + 0] = v.x;
        Tl[rr * 16 + rl][q * 4 + 1] = v.y;
        Tl[rr * 16 + rl][q * 4 + 2] = v.z;
        Tl[rr * 16 + rl][q * 4 + 3] = v.w;
    }
    __syncthreads();
    #pragma unroll
    for (int ss = 0; ss < 4; ss++) {
        const int kl = ss * 16 + rl;        // local k (src col)
        const int cq = q * 4;               // local c (src row)
        float4 v;
        v.x = Tl[cq + 0][kl]; v.y = Tl[cq + 1][kl];
        v.z = Tl[cq + 2][kl]; v.w = Tl[cq + 3][kl];
        *(float4*)(dst + (size_t)(tc * 64 + kl) * NN + tr * 64 + cq) = v;
    }
}

// hidfix = feat * mask (step 0).  grid 512, 256 threads, float4.
__global__ __launch_bounds__(256) void maskmul_k(
    const float* __restrict__ feat,
    const float* __restrict__ mask,
    float* __restrict__ dst)
{
    const int i = blockIdx.x * 256 + threadIdx.x;   // over 2048*64 float4s
    const float4 f = ((const float4*)feat)[i];
    const float mv = mask[i >> 6];
    ((float4*)dst)[i] = make_float4(f.x * mv, f.y * mv, f.z * mv, f.w * mv);
}

// x = hidfix @ aggW^T + aggB.  256 blocks x 512 threads.
// Thread = (col c, k-half). A-loads are wave-uniform -> scalar cache.
// Wt stream is coalesced 4B/lane. One LDS reduce combines the k-halves.
__global__ __launch_bounds__(512) void gemmA_k(
    const float* __restrict__ A,    // [2048][256]
    const float* __restrict__ Wt,   // [256][256] k-major
    const float* __restrict__ bias, // [256]
    float* __restrict__ O)          // [2048][256]
{
    __shared__ float red[256][9];
    const int tid = threadIdx.x;
    const int c = tid & 255;
    const int kh = tid >> 8;        // 0 or 1
    const int r0 = blockIdx.x * 8;
    const float* Ab = A + (size_t)r0 * NN;
    float acc[8] = {};
    const int kbeg = kh * 128;
    #pragma unroll 4
    for (int k = kbeg; k < kbeg + 128; ++k) {
        const float w = Wt[(size_t)k * NN + c];
        #pragma unroll
        for (int r = 0; r < 8; ++r)
            acc[r] += Ab[r * NN + k] * w;      // Ab[...] uniform -> s_load
    }
    if (kh) {
        #pragma unroll
        for (int r = 0; r < 8; ++r) red[c][r] = acc[r];
    }
    __syncthreads();
    if (!kh) {
        const float b = bias[c];
        #pragma unroll
        for (int r = 0; r < 8; ++r)
            O[(size_t)(r0 + r) * NN + c] = acc[r] + red[c][r] + b;
    }
}

// [p | xU1] = x @ [W1 | U1]^T.  256 blocks x 512 threads, 1 col/thread, full k.
__global__ __launch_bounds__(512) void gemmB_k(
    const float* __restrict__ x,     // [2048][256]
    const float* __restrict__ W1t,   // [256][256] k-major
    const float* __restrict__ U1t,   // [256][256] k-major
    float* __restrict__ p,           // [2048][256]
    float* __restrict__ xU1)         // [2048][256]
{
    const int tid = threadIdx.x;
    const int c = tid & 255;
    const int half = tid >> 8;                 // wave-uniform
    const float* Wt = half ? U1t : W1t;
    float* O = half ? xU1 : p;
    const int r0 = blockIdx.x * 8;
    const float* Ab = x + (size_t)r0 * NN;
    float acc[8] = {};
    #pragma unroll 4
    for (int k = 0; k < NN; ++k) {
        const float w = Wt[(size_t)k * NN + c];
        #pragma unroll
        for (int r = 0; r < 8; ++r)
            acc[r] += Ab[r * NN + k] * w;
    }
    #pragma unroll
    for (int r = 0; r < 8; ++r)
        O[(size_t)(r0 + r) * NN + c] = acc[r];
}

// Per batch b: agg[c] = sigmoid(softmax_s(p[b,:,c]) . x[b,:,c])
// acc[c] = agg @ U2^T + updB;  then for its s-chunk:
//   mask mode: hidfix = (xU1 + acc) * mask
//   out  mode: out    =  xU1 + acc
// grid (8 s-chunks, 16 batches) x 256 threads.
__global__ __launch_bounds__(256) void softfix_k(
    const float* __restrict__ p,     // [16][128][256]
    const float* __restrict__ x,
    const float* __restrict__ U2t,   // [256][256] k-major
    const float* __restrict__ updBi, // [256]
    const float* __restrict__ xU1,   // [16][128][256]
    const float* __restrict__ mask,  // [16][128] or null (out mode)
    float* __restrict__ dst)
{
    __shared__ float sagg[NN];
    const int b = blockIdx.y;
    const int c = threadIdx.x;
    const float* pb = p + (size_t)b * LL * NN + c;
    const float* xb = x + (size_t)b * LL * NN + c;
    float m = -1e30f;
    #pragma unroll 8
    for (int s = 0; s < LL; ++s) m = fmaxf(m, pb[s * NN]);
    float den = 0.f, num = 0.f;
    #pragma unroll 8
    for (int s = 0; s < LL; ++s) {
        const float e = __expf(pb[s * NN] - m);
        den += e; num += e * xb[s * NN];
    }
    const float a = num / den;
    sagg[c] = 1.f / (1.f + __expf(-a));
    __syncthreads();
    float acc = updBi[c];
    for (int j = 0; j < NN; j += 4) {
        const float4 s4 = *(const float4*)&sagg[j];   // LDS broadcast b128
        acc += s4.x * U2t[(size_t)(j + 0) * NN + c];
        acc += s4.y * U2t[(size_t)(j + 1) * NN + c];
        acc += s4.z * U2t[(size_t)(j + 2) * NN + c];
        acc += s4.w * U2t[(size_t)(j + 3) * NN + c];
    }
    const int s0 = blockIdx.x * (LL / 8);
    const float* xu = xU1 + ((size_t)b * LL + s0) * NN + c;
    float* d = dst + ((size_t)b * LL + s0) * NN + c;
    #pragma unroll
    for (int s = 0; s < LL / 8; ++s) {
        float v = xu[s * NN] + acc;
        if (mask) v *= mask[b * LL + s0 + s];
        d[s * NN] = v;
    }
}

extern "C" void kernel_launch(void* const* d_in, const int* in_sizes, int n_in,
                              void* d_out, int out_size, void* d_ws, size_t ws_size,
                              hipStream_t stream) {
    const float* feat  = (const float*)d_in[0]; // [16][128][256]
    const float* mask  = (const float*)d_in[1]; // [16][128]
    const float* aggW  = (const float*)d_in[2]; // [3][256][256]
    const float* aggB  = (const float*)d_in[3]; // [3][256]
    const float* attnW = (const float*)d_in[4]; // [3][256][512]
    // d_in[5] = attnB: cancels in softmax (constant along the s axis)
    const float* updW  = (const float*)d_in[6]; // [3][256][512]
    const float* updB  = (const float*)d_in[7]; // [3][256]

    const size_t MAT = (size_t)RR * NN;   // 524288
    float* hidfix = (float*)d_ws;
    float* xbuf   = hidfix + MAT;
    float* pbuf   = xbuf + MAT;
    float* xU1buf = pbuf + MAT;
    float* WtB    = xU1buf + MAT;         // 12 * 65536 floats
    float* aggWt  = WtB;
    float* W1t    = WtB + 3 * (size_t)NN * NN;
    float* U1t    = WtB + 6 * (size_t)NN * NN;
    float* U2t    = WtB + 9 * (size_t)NN * NN;

    // weights -> k-major transposes (once)
    trans_k<<<dim3(16, 12), 256, 0, stream>>>(aggW, attnW, updW, WtB);
    // step-0 A: hidfix = feat * mask
    maskmul_k<<<512, 256, 0, stream>>>(feat, mask, hidfix);

    for (int i = 0; i < 3; i++) {
        if (i > 0) {
            // hidfix = (xU1 + agg@U2^T + updB) * mask   (uses step i-1 tensors)
            softfix_k<<<dim3(8, BSZ), 256, 0, stream>>>(
                pbuf, xbuf, U2t + (size_t)(i - 1) * NN * NN,
                updB + (size_t)(i - 1) * NN, xU1buf, mask, hidfix);
        }
        // x = hidfix @ aggW_i^T + aggB_i
        gemmA_k<<<256, 512, 0, stream>>>(
            hidfix, aggWt + (size_t)i * NN * NN, aggB + (size_t)i * NN, xbuf);
        // [p | xU1] = x @ [W1_i | U1_i]^T
        gemmB_k<<<256, 512, 0, stream>>>(
            xbuf, W1t + (size_t)i * NN * NN, U1t + (size_t)i * NN * NN,
            pbuf, xU1buf);
    }
    // out = xU1 + agg@U2^T + updB   (step-2 tensors, no mask)
    softfix_k<<<dim3(8, BSZ), 256, 0, stream>>>(
        pbuf, xbuf, U2t + (size_t)2 * NN * NN,
        updB + (size_t)2 * NN, xU1buf, nullptr, (float*)d_out);
}